// Round 23
// baseline (192.859 us; speedup 1.0000x reference)
//
#include <hip/hip_runtime.h>
#include <hip/hip_bf16.h>
#include <cstdint>

#define NB 4
#define NS 2048
#define ND 1024
#define NH 16
#define NDH 64
#define NM (NB*NS)       // 8192
#define N3D (3*ND)       // 3072

typedef __attribute__((ext_vector_type(8))) short short8;
typedef __attribute__((ext_vector_type(4))) float f32x4;
typedef __attribute__((ext_vector_type(4))) unsigned short us4;
typedef __attribute__((ext_vector_type(4))) unsigned int uint4v;

__device__ __forceinline__ float bf2f(unsigned short u) {
  unsigned int i = ((unsigned int)u) << 16;
  return __builtin_bit_cast(float, i);
}
__device__ __forceinline__ unsigned short f2bf(float f) {
  unsigned int i = __builtin_bit_cast(unsigned int, f);
  i = (i + 0x7FFFu + ((i >> 16) & 1u)) >> 16;
  return (unsigned short)i;
}
// packed 2x bf16 (RNE) from two f32 — T12 recipe, no builtin on gfx950
__device__ __forceinline__ unsigned int cvtpk_bf16(float lo, float hi) {
  unsigned int r;
  asm("v_cvt_pk_bf16_f32 %0, %1, %2" : "=v"(r) : "v"(lo), "v"(hi));
  return r;
}

#define GLD16(g, l) __builtin_amdgcn_global_load_lds( \
    (__attribute__((address_space(1))) void*)(void*)(g), \
    (__attribute__((address_space(3))) void*)(l), 16, 0, 0)

// ------------------------------------------------------------ f32 -> bf16 cast
__global__ __launch_bounds__(256) void cvt_bf16_k(
    const float* __restrict__ in, unsigned short* __restrict__ out, int n)
{
  const int i = (blockIdx.x * 256 + threadIdx.x) * 4;
  if (i + 3 < n) {
    const f32x4 v = *(const f32x4*)(in + i);
    us4 o = {f2bf(v[0]), f2bf(v[1]), f2bf(v[2]), f2bf(v[3])};
    *(us4*)(out + i) = o;
  }
}

// --------------------------------------------- f32 [rows][cols] -> bf16 [cols][rows]
__global__ __launch_bounds__(256) void transpose_cvt_k(
    const float* __restrict__ in, unsigned short* __restrict__ out,
    int rows, int cols)
{
  __shared__ unsigned short tile[32][33];
  const int c0 = blockIdx.x * 32, r0 = blockIdx.y * 32;
  const int tx = threadIdx.x & 31, ty = threadIdx.x >> 5;   // ty 0..7
  #pragma unroll
  for (int i = ty; i < 32; i += 8)
    tile[i][tx] = f2bf(in[(size_t)(r0 + i) * cols + (c0 + tx)]);
  __syncthreads();
  #pragma unroll
  for (int i = ty; i < 32; i += 8)
    out[(size_t)(c0 + i) * rows + (r0 + tx)] = tile[tx][i];
}

// ---------------------------------- V columns of qkv -> Vt[bh][d=64][s=2048]
__global__ __launch_bounds__(256) void vt_transpose_k(
    const unsigned short* __restrict__ qkv, unsigned short* __restrict__ vt)
{
  __shared__ unsigned short tile[32][33];
  const int dt = blockIdx.x & 1;           // 2 d-tiles
  const int st = (blockIdx.x >> 1) & 63;   // 64 s-tiles
  const int bh = blockIdx.x >> 7;          // 64 (b,h)
  const int b = bh >> 4, h = bh & 15;
  const int tx = threadIdx.x & 31, ty = threadIdx.x >> 5;
  const int s0 = st * 32, d0 = dt * 32;
  const unsigned short* src = qkv + (size_t)b * NS * N3D + 2 * ND + h * NDH;
  #pragma unroll
  for (int i = ty; i < 32; i += 8)
    tile[i][tx] = src[(size_t)(s0 + i) * N3D + d0 + tx];
  __syncthreads();
  unsigned short* dst = vt + (size_t)bh * NDH * NS;
  #pragma unroll
  for (int i = ty; i < 32; i += 8)
    dst[(size_t)(d0 + i) * NS + s0 + tx] = tile[tx][i];
}

// ------------------------------------------------- GEMM  C = A * Bt^T + bias
// A[M][K] bf16 row-major, Bt[N][K] bf16 row-major, f32 bias. 128x128 tile,
// BK=64, 4 waves, dbuf LDS + one barrier per K-step, 8-quad bank swizzle.
// R23: bn-major XCD partitioning. GEMM2 (B=2MB, L2-fit) runs ~4x faster
// blocks than GEMM1 (B=6MB, L2-thrash) with identical code — so give each
// XCD nbn/8 bn-columns: concurrent blocks in an XCD share ONE B panel
// (256KB, L2-resident); A panels stream via L3 (everything L3-fits).
// Bijective: xcd=bid&7, t=bid>>3, bn=xcd*(nbn/8)+t/nbm, bm=t%nbm
// (nbn%8==0 for both GEMMs). Dispatch fills bm-major per XCD.
template<bool OUT_F32>
__global__ __launch_bounds__(256) void gemm_bt_bias(
    const unsigned short* __restrict__ A,
    const unsigned short* __restrict__ Bt,
    const float* __restrict__ bias,
    unsigned short* __restrict__ Cb,
    float* __restrict__ Cf,
    int M, int N, int K)
{
  __shared__ __align__(16) unsigned short Alds[2][128 * 64];
  __shared__ __align__(16) unsigned short Blds[2][128 * 64];
  const int nbn = N >> 7;
  const int nbm = M >> 7;
  const int xcd = blockIdx.x & 7;
  const int t   = blockIdx.x >> 3;
  const int bn  = xcd * (nbn >> 3) + t / nbm;
  const int bm  = t % nbm;
  const int m0 = bm << 7, n0 = bn << 7;
  const int w = threadIdx.x >> 6, l = threadIdx.x & 63;
  const int wr = w >> 1, wc = w & 1;
  const int lr = l & 15, lg = l >> 4;

  // staging: lane l -> rows w*32+(l>>3)+{0,8,16,24}, chunk l&7 (of 8);
  // source chunk pre-swizzled by row&7 so linear LDS writes land swizzled.
  const int sc = (l & 7) ^ (l >> 3);
  const unsigned short* gA = A + (size_t)(m0 + w * 32 + (l >> 3)) * K + sc * 8;
  const unsigned short* gB = Bt + (size_t)(n0 + w * 32 + (l >> 3)) * K + sc * 8;
  const int lwoff = (w * 32) * 64;   // wave's element offset in the tile

  auto stage = [&](int buf, int k0) {
    unsigned short* la = &Alds[buf][lwoff];
    unsigned short* lb = &Blds[buf][lwoff];
    #pragma unroll
    for (int r = 0; r < 4; ++r) {
      GLD16(gA + k0 + (size_t)(8 * r) * K, la + (8 * r) * 64);
      GLD16(gB + k0 + (size_t)(8 * r) * K, lb + (8 * r) * 64);
    }
  };

  f32x4 acc[4][4] = {};
  const int rxor = lr & 7;           // read-side XOR (row&7 == lr&7)

  stage(0, 0);
  __syncthreads();                   // prologue: only exposed stage latency

  #pragma unroll 1
  for (int it = 0; it < (K >> 6); ++it) {
    const int buf = it & 1;
    const int k0 = it << 6;
    if (k0 + 64 < K) stage(buf ^ 1, k0 + 64);   // async; drains at barrier below

    #pragma unroll
    for (int kk = 0; kk < 2; ++kk) {
      const int rch = ((kk * 4 + lg) ^ rxor) << 3;
      short8 a[4], b[4];
      #pragma unroll
      for (int i = 0; i < 4; ++i)
        a[i] = *(const short8*)(&Alds[buf][(wr * 64 + i * 16 + lr) * 64 + rch]);
      #pragma unroll
      for (int j = 0; j < 4; ++j)
        b[j] = *(const short8*)(&Blds[buf][(wc * 64 + j * 16 + lr) * 64 + rch]);

      #pragma unroll
      for (int i = 0; i < 4; ++i)
        #pragma unroll
        for (int j = 0; j < 4; ++j)
          acc[i][j] = __builtin_amdgcn_mfma_f32_16x16x32_bf16(a[i], b[j], acc[i][j], 0, 0, 0);
    }

    __syncthreads();   // joins readers of buf + drains stage(buf^1) (landed)
  }

  #pragma unroll
  for (int j = 0; j < 4; ++j) {
    const int col = n0 + wc * 64 + j * 16 + lr;
    const float bv = bias[col];
    #pragma unroll
    for (int i = 0; i < 4; ++i) {
      #pragma unroll
      for (int r = 0; r < 4; ++r) {
        const int row = m0 + wr * 64 + i * 16 + lg * 4 + r;
        const float v = acc[i][j][r] + bv;
        if (OUT_F32) Cf[(size_t)row * N + col] = v;
        else         Cb[(size_t)row * N + col] = f2bf(v);
      }
    }
  }
}

// ----------------------------------------------------- causal flash attention
// R21 structure (8-wave blocks x 128 q-rows; KVBLK=128 staged as 2x64-key
// subtiles, 17 barriers/block; pre-swizzled source, 0 bank conflicts;
// no-max-tracking exp2 softmax; T5 setprio around MFMA clusters). Unchanged.
__global__ __launch_bounds__(512) void attn_fwd(
    const unsigned short* __restrict__ qkv,
    const unsigned short* __restrict__ Vt,
    unsigned short* __restrict__ out)
{
  __shared__ __align__(16) char Kl[2][2][64 * 128];  // [buf][subtile][row*128+swz]
  __shared__ __align__(16) char Vl[2][2][64 * 128];  // rows = d, cols = key

  const int bid = blockIdx.x;
  const int bh = bid & 63;               // XCD = bh % 8 stable
  const int slot = bid >> 6;             // 0..7
  const int b = bh >> 4, h = bh & 15;
  const int w = threadIdx.x >> 6, l = threadIdx.x & 63;   // w 0..7
  const int lr = l & 15, lg = l >> 4;

  const size_t rs = N3D;
  const unsigned short* Qb = qkv + (size_t)b * NS * rs + (size_t)h * NDH;
  const unsigned short* Kb = Qb + ND;
  const unsigned short* VtB = Vt + (size_t)bh * NDH * NS;

  const int srow = l >> 3;                               // 0..7
  const int sw = (((l & 7) * 16) ^ (srow << 4)) >> 1;    // element offset
  const unsigned short* KsrcBase = Kb + (size_t)(8 * w + srow) * rs + sw;
  const unsigned short* VsrcBase = VtB + (size_t)(8 * w + srow) * NS + sw;
  const int ldsRow0 = (8 * w) * 128;                     // wave's dest base

  const float QSCALE = 0.125f * 1.44269504f;   // exp2-domain
  const int ksw = (lr & 7) << 4;               // read-side XOR swizzle

  #pragma unroll 1
  for (int pass = 0; pass < 2; ++pass) {
    const int qt = pass == 0 ? slot : 15 - slot;   // q-tile 0..15 (128 rows)
    const int q0 = qt * 128 + w * 16;              // wave's 16 q-rows
    const int T2 = qt + 1;                         // 128-key tiles this pass

    // Q fragment for rows q0+lr, pre-scaled (bf16 round, ~0.2% rel err)
    short8 qf[2];
    {
      const unsigned short* qrow = Qb + (size_t)(q0 + lr) * rs + lg * 8;
      qf[0] = *(const short8*)(qrow);
      qf[1] = *(const short8*)(qrow + 32);
      #pragma unroll
      for (int j = 0; j < 8; ++j) {
        qf[0][j] = (short)f2bf(bf2f((unsigned short)qf[0][j]) * QSCALE);
        qf[1][j] = (short)f2bf(bf2f((unsigned short)qf[1][j]) * QSCALE);
      }
    }

    float l_run = 0.f;                 // per-lane PARTIAL row sum
    f32x4 o[4] = {};

    auto stage = [&](int buf, int kt2) {
      const int kb = kt2 << 7;
      GLD16(KsrcBase + (size_t)kb * rs,        &Kl[buf][0][ldsRow0]);
      GLD16(KsrcBase + (size_t)(kb + 64) * rs, &Kl[buf][1][ldsRow0]);
      GLD16(VsrcBase + kb,                     &Vl[buf][0][ldsRow0]);
      GLD16(VsrcBase + kb + 64,                &Vl[buf][1][ldsRow0]);
    };

    stage(0, 0);
    __syncthreads();   // compiler drains vmcnt before s_barrier

    #pragma unroll 1
    for (int kt2 = 0; kt2 < T2; ++kt2) {
      const int cur = kt2 & 1;
      if (kt2 + 1 < T2) stage(cur ^ 1, kt2 + 1);   // async, lands by next barrier

      #pragma unroll
      for (int st = 0; st < 2; ++st) {
        const int kbase = kt2 * 128 + st * 64;
        if (kbase > q0 + 15) continue;   // wave-uniform: skip fully-masked

        // K fragments from LDS (swizzled ds_read_b128)
        short8 kf[4][2];
        #pragma unroll
        for (int ks = 0; ks < 4; ++ks) {
          const char* rowp = &Kl[cur][st][(ks * 16 + lr) * 128];
          kf[ks][0] = *(const short8*)(rowp + ((lg * 16) ^ ksw));
          kf[ks][1] = *(const short8*)(rowp + ((64 + lg * 16) ^ ksw));
        }

        // swapped QK^T: s[ks] = S^T[key=kbase+ks*16+lg*4+r][q=q0+lr]
        f32x4 s[4] = {};
        __builtin_amdgcn_s_setprio(1);
        #pragma unroll
        for (int ks = 0; ks < 4; ++ks) {
          s[ks] = __builtin_amdgcn_mfma_f32_16x16x32_bf16(kf[ks][0], qf[0], s[ks], 0, 0, 0);
          s[ks] = __builtin_amdgcn_mfma_f32_16x16x32_bf16(kf[ks][1], qf[1], s[ks], 0, 0, 0);
        }
        __builtin_amdgcn_s_setprio(0);

        // V fragments (ds latency overlaps the softmax VALU below)
        short8 vf[4][2];
        #pragma unroll
        for (int nb = 0; nb < 4; ++nb) {
          const char* rowp = &Vl[cur][st][(nb * 16 + lr) * 128];
          vf[nb][0] = *(const short8*)(rowp + ((lg * 16) ^ ksw));
          vf[nb][1] = *(const short8*)(rowp + ((64 + lg * 16) ^ ksw));
        }

        const bool domask = (kbase + 63 > q0);   // wave-uniform (diag tiles)
        const int qi = q0 + lr;
        // un-shifted exponentials (bounded-score proof, R16); mask -> 0
        float p[16];
        if (domask) {
          #pragma unroll
          for (int ks = 0; ks < 4; ++ks)
            #pragma unroll
            for (int r = 0; r < 4; ++r)
              p[ks * 4 + r] = (kbase + ks * 16 + lg * 4 + r > qi)
                                ? 0.f : exp2f(s[ks][r]);
        } else {
          #pragma unroll
          for (int ks = 0; ks < 4; ++ks)
            #pragma unroll
            for (int r = 0; r < 4; ++r)
              p[ks * 4 + r] = exp2f(s[ks][r]);
        }
        // per-lane PARTIAL row sum (no shuffles; reduced once in epilogue)
        float s0 = (p[0] + p[1]) + (p[2] + p[3]);
        float s1 = (p[4] + p[5]) + (p[6] + p[7]);
        float s2 = (p[8] + p[9]) + (p[10] + p[11]);
        float s3 = (p[12] + p[13]) + (p[14] + p[15]);
        l_run += (s0 + s1) + (s2 + s3);

        // pack P to bf16 pairs: A_ks = keys ks*16+lg*4+{0,1}, B_ks = {2,3}
        unsigned A0 = cvtpk_bf16(p[0],  p[1]),  B0 = cvtpk_bf16(p[2],  p[3]);
        unsigned A1 = cvtpk_bf16(p[4],  p[5]),  B1 = cvtpk_bf16(p[6],  p[7]);
        unsigned A2 = cvtpk_bf16(p[8],  p[9]),  B2 = cvtpk_bf16(p[10], p[11]);
        unsigned A3 = cvtpk_bf16(p[12], p[13]), B3 = cvtpk_bf16(p[14], p[15]);

        // in-register transpose to PV A-fragment layout (VALU, no LDS)
        asm("v_permlane32_swap_b32 %0, %1" : "+v"(A0), "+v"(A1));
        asm("v_permlane16_swap_b32 %0, %1" : "+v"(A0), "+v"(A1));
        asm("v_permlane32_swap_b32 %0, %1" : "+v"(B0), "+v"(B1));
        asm("v_permlane16_swap_b32 %0, %1" : "+v"(B0), "+v"(B1));
        asm("v_permlane32_swap_b32 %0, %1" : "+v"(A2), "+v"(A3));
        asm("v_permlane16_swap_b32 %0, %1" : "+v"(A2), "+v"(A3));
        asm("v_permlane32_swap_b32 %0, %1" : "+v"(B2), "+v"(B3));
        asm("v_permlane16_swap_b32 %0, %1" : "+v"(B2), "+v"(B3));

        uint4v u0 = {A0, B0, A1, B1};   // pf0: keys lg*8+0..7
        uint4v u1 = {A2, B2, A3, B3};   // pf1: keys 32+lg*8+0..7
        short8 pf0 = __builtin_bit_cast(short8, u0);
        short8 pf1 = __builtin_bit_cast(short8, u1);

        __builtin_amdgcn_s_setprio(1);
        #pragma unroll
        for (int nb = 0; nb < 4; ++nb)
          o[nb] = __builtin_amdgcn_mfma_f32_16x16x32_bf16(pf0, vf[nb][0], o[nb], 0, 0, 0);
        #pragma unroll
        for (int nb = 0; nb < 4; ++nb)
          o[nb] = __builtin_amdgcn_mfma_f32_16x16x32_bf16(pf1, vf[nb][1], o[nb], 0, 0, 0);
        __builtin_amdgcn_s_setprio(0);
      }

      __syncthreads();   // joins waves; drains vmcnt (stage done) + LDS reads
    }

    // epilogue: reduce the per-lane l_run partials (once per pass), normalize
    {
      float lt = l_run;
      lt += __shfl_xor(lt, 16);
      lt += __shfl_xor(lt, 32);
      #pragma unroll
      for (int rr = 0; rr < 4; ++rr) {
        const float lq = __shfl(lt, lg * 4 + rr);
        const float inv = 1.0f / lq;
        const int qi = q0 + lg * 4 + rr;
        #pragma unroll
        for (int nb = 0; nb < 4; ++nb)
          out[(size_t)(b * NS + qi) * ND + h * NDH + nb * 16 + lr] = f2bf(o[nb][rr] * inv);
      }
    }
  }
}

// --------------------------------------------------------------------- launch
extern "C" void kernel_launch(void* const* d_in, const int* in_sizes, int n_in,
                              void* d_out, int out_size, void* d_ws, size_t ws_size,
                              hipStream_t stream) {
  const float* x     = (const float*)d_in[0];
  const float* w_in  = (const float*)d_in[1];
  const float* b_in  = (const float*)d_in[2];
  const float* w_out = (const float*)d_in[3];
  const float* b_out = (const float*)d_in[4];
  float* out = (float*)d_out;

  char* ws = (char*)d_ws;
  size_t off = 0;
  unsigned short* x_bf    = (unsigned short*)(ws + off); off += (size_t)NM * ND * 2;    // 16 MiB
  unsigned short* qkv     = (unsigned short*)(ws + off); off += (size_t)NM * N3D * 2;   // 48 MiB
  unsigned short* attn    = (unsigned short*)(ws + off); off += (size_t)NM * ND * 2;    // 16 MiB
  unsigned short* w_in_t  = (unsigned short*)(ws + off); off += (size_t)N3D * ND * 2;   //  6 MiB
  unsigned short* w_out_t = (unsigned short*)(ws + off); off += (size_t)ND * ND * 2;    //  2 MiB
  // Vt aliases x_bf: x_bf is dead after GEMM1, vt_transpose runs after GEMM1.
  unsigned short* vt = x_bf;                                                            // 16 MiB

  // x -> bf16
  cvt_bf16_k<<<dim3((NM * ND) / (256 * 4)), 256, 0, stream>>>(x, x_bf, NM * ND);
  // weight transposes + cast: w[K][N] f32 -> wt[N][K] bf16
  transpose_cvt_k<<<dim3(N3D / 32, ND / 32), 256, 0, stream>>>(w_in, w_in_t, ND, N3D);
  transpose_cvt_k<<<dim3(ND / 32, ND / 32), 256, 0, stream>>>(w_out, w_out_t, ND, ND);

  // qkv = x @ w_in + b_in            (bf16 out)
  gemm_bt_bias<false><<<dim3((NM / 128) * (N3D / 128)), 256, 0, stream>>>(
      x_bf, w_in_t, b_in, qkv, nullptr, NM, N3D, ND);

  // V -> Vt (transposed per head)
  vt_transpose_k<<<dim3(64 * 64 * 2), 256, 0, stream>>>(qkv, vt);

  // attention: 512 blocks x 512 threads (8 waves, 128 q-rows; pairing qt/15-qt)
  attn_fwd<<<dim3(64 * 8), 512, 0, stream>>>(qkv, vt, attn);

  // out = attn @ w_out + b_out       (f32 out)
  gemm_bt_bias<true><<<dim3((NM / 128) * (ND / 128)), 256, 0, stream>>>(
      attn, w_out_t, b_out, nullptr, out, NM, ND, ND);
}

// Round 24
// 179.630 us; speedup vs baseline: 1.0736x; 1.0736x over previous
//
#include <hip/hip_runtime.h>
#include <hip/hip_bf16.h>
#include <cstdint>

#define NB 4
#define NS 2048
#define ND 1024
#define NH 16
#define NDH 64
#define NM (NB*NS)       // 8192
#define N3D (3*ND)       // 3072

typedef __attribute__((ext_vector_type(8))) short short8;
typedef __attribute__((ext_vector_type(4))) float f32x4;
typedef __attribute__((ext_vector_type(4))) unsigned short us4;
typedef __attribute__((ext_vector_type(4))) unsigned int uint4v;

__device__ __forceinline__ float bf2f(unsigned short u) {
  unsigned int i = ((unsigned int)u) << 16;
  return __builtin_bit_cast(float, i);
}
__device__ __forceinline__ unsigned short f2bf(float f) {
  unsigned int i = __builtin_bit_cast(unsigned int, f);
  i = (i + 0x7FFFu + ((i >> 16) & 1u)) >> 16;
  return (unsigned short)i;
}
// packed 2x bf16 (RNE) from two f32 — T12 recipe, no builtin on gfx950
__device__ __forceinline__ unsigned int cvtpk_bf16(float lo, float hi) {
  unsigned int r;
  asm("v_cvt_pk_bf16_f32 %0, %1, %2" : "=v"(r) : "v"(lo), "v"(hi));
  return r;
}

#define GLD16(g, l) __builtin_amdgcn_global_load_lds( \
    (__attribute__((address_space(1))) void*)(void*)(g), \
    (__attribute__((address_space(3))) void*)(l), 16, 0, 0)

// ------------------------------------------------------------ f32 -> bf16 cast
__global__ __launch_bounds__(256) void cvt_bf16_k(
    const float* __restrict__ in, unsigned short* __restrict__ out, int n)
{
  const int i = (blockIdx.x * 256 + threadIdx.x) * 4;
  if (i + 3 < n) {
    const f32x4 v = *(const f32x4*)(in + i);
    us4 o = {f2bf(v[0]), f2bf(v[1]), f2bf(v[2]), f2bf(v[3])};
    *(us4*)(out + i) = o;
  }
}

// --------------------------------------------- f32 [rows][cols] -> bf16 [cols][rows]
__global__ __launch_bounds__(256) void transpose_cvt_k(
    const float* __restrict__ in, unsigned short* __restrict__ out,
    int rows, int cols)
{
  __shared__ unsigned short tile[32][33];
  const int c0 = blockIdx.x * 32, r0 = blockIdx.y * 32;
  const int tx = threadIdx.x & 31, ty = threadIdx.x >> 5;   // ty 0..7
  #pragma unroll
  for (int i = ty; i < 32; i += 8)
    tile[i][tx] = f2bf(in[(size_t)(r0 + i) * cols + (c0 + tx)]);
  __syncthreads();
  #pragma unroll
  for (int i = ty; i < 32; i += 8)
    out[(size_t)(c0 + i) * rows + (r0 + tx)] = tile[tx][i];
}

// ---------------------------------- V columns of qkv -> Vt[bh][d=64][s=2048]
__global__ __launch_bounds__(256) void vt_transpose_k(
    const unsigned short* __restrict__ qkv, unsigned short* __restrict__ vt)
{
  __shared__ unsigned short tile[32][33];
  const int dt = blockIdx.x & 1;           // 2 d-tiles
  const int st = (blockIdx.x >> 1) & 63;   // 64 s-tiles
  const int bh = blockIdx.x >> 7;          // 64 (b,h)
  const int b = bh >> 4, h = bh & 15;
  const int tx = threadIdx.x & 31, ty = threadIdx.x >> 5;
  const int s0 = st * 32, d0 = dt * 32;
  const unsigned short* src = qkv + (size_t)b * NS * N3D + 2 * ND + h * NDH;
  #pragma unroll
  for (int i = ty; i < 32; i += 8)
    tile[i][tx] = src[(size_t)(s0 + i) * N3D + d0 + tx];
  __syncthreads();
  unsigned short* dst = vt + (size_t)bh * NDH * NS;
  #pragma unroll
  for (int i = ty; i < 32; i += 8)
    dst[(size_t)(d0 + i) * NS + s0 + tx] = tile[tx][i];
}

// ------------------------------------------------- GEMM  C = A * Bt^T + bias
// A[M][K] bf16 row-major, Bt[N][K] bf16 row-major, f32 bias. 128x128 tile,
// BK=64, 4 waves, dbuf LDS + one barrier per K-step, 8-quad bank swizzle.
// R24: SQUARE concurrent L2 footprint. R22 (bm-slice x all-bn) thrashed B
// (6MB); R23 (bn-major) thrashed A (64 concurrent A panels = 16MB, FETCH
// 200MB — the "share one B panel" reasoning optimized the small operand and
// streamed the big one). Fix: 2D chiplet grid 4(bm) x 2(bn); per-XCD region
// 16bm x 12bn, bn-fastest order -> 64 concurrent blocks ~ 5.3bm x 12bn ->
// A 1.4MB + B 3MB = 4.4MB ~ L2 -> stage loads hit L2 (~200cy, covered by
// the BK=64 body). Bijective: needs nbn%2==0, nbm%4==0 (both GEMMs ok).
template<bool OUT_F32>
__global__ __launch_bounds__(256) void gemm_bt_bias(
    const unsigned short* __restrict__ A,
    const unsigned short* __restrict__ Bt,
    const float* __restrict__ bias,
    unsigned short* __restrict__ Cb,
    float* __restrict__ Cf,
    int M, int N, int K)
{
  __shared__ __align__(16) unsigned short Alds[2][128 * 64];
  __shared__ __align__(16) unsigned short Blds[2][128 * 64];
  const int nbn = N >> 7;
  const int nbm = M >> 7;
  const int xcd = blockIdx.x & 7;
  const int t   = blockIdx.x >> 3;
  const int bnpx = nbn >> 1;           // bn per XCD (chiplet grid 4m x 2n)
  const int bn  = (xcd & 1) * bnpx + t % bnpx;
  const int bm  = (xcd >> 1) * (nbm >> 2) + t / bnpx;
  const int m0 = bm << 7, n0 = bn << 7;
  const int w = threadIdx.x >> 6, l = threadIdx.x & 63;
  const int wr = w >> 1, wc = w & 1;
  const int lr = l & 15, lg = l >> 4;

  // staging: lane l -> rows w*32+(l>>3)+{0,8,16,24}, chunk l&7 (of 8);
  // source chunk pre-swizzled by row&7 so linear LDS writes land swizzled.
  const int sc = (l & 7) ^ (l >> 3);
  const unsigned short* gA = A + (size_t)(m0 + w * 32 + (l >> 3)) * K + sc * 8;
  const unsigned short* gB = Bt + (size_t)(n0 + w * 32 + (l >> 3)) * K + sc * 8;
  const int lwoff = (w * 32) * 64;   // wave's element offset in the tile

  auto stage = [&](int buf, int k0) {
    unsigned short* la = &Alds[buf][lwoff];
    unsigned short* lb = &Blds[buf][lwoff];
    #pragma unroll
    for (int r = 0; r < 4; ++r) {
      GLD16(gA + k0 + (size_t)(8 * r) * K, la + (8 * r) * 64);
      GLD16(gB + k0 + (size_t)(8 * r) * K, lb + (8 * r) * 64);
    }
  };

  f32x4 acc[4][4] = {};
  const int rxor = lr & 7;           // read-side XOR (row&7 == lr&7)

  stage(0, 0);
  __syncthreads();                   // prologue: only exposed stage latency

  #pragma unroll 1
  for (int it = 0; it < (K >> 6); ++it) {
    const int buf = it & 1;
    const int k0 = it << 6;
    if (k0 + 64 < K) stage(buf ^ 1, k0 + 64);   // async; drains at barrier below

    #pragma unroll
    for (int kk = 0; kk < 2; ++kk) {
      const int rch = ((kk * 4 + lg) ^ rxor) << 3;
      short8 a[4], b[4];
      #pragma unroll
      for (int i = 0; i < 4; ++i)
        a[i] = *(const short8*)(&Alds[buf][(wr * 64 + i * 16 + lr) * 64 + rch]);
      #pragma unroll
      for (int j = 0; j < 4; ++j)
        b[j] = *(const short8*)(&Blds[buf][(wc * 64 + j * 16 + lr) * 64 + rch]);

      #pragma unroll
      for (int i = 0; i < 4; ++i)
        #pragma unroll
        for (int j = 0; j < 4; ++j)
          acc[i][j] = __builtin_amdgcn_mfma_f32_16x16x32_bf16(a[i], b[j], acc[i][j], 0, 0, 0);
    }

    __syncthreads();   // joins readers of buf + drains stage(buf^1) (landed)
  }

  #pragma unroll
  for (int j = 0; j < 4; ++j) {
    const int col = n0 + wc * 64 + j * 16 + lr;
    const float bv = bias[col];
    #pragma unroll
    for (int i = 0; i < 4; ++i) {
      #pragma unroll
      for (int r = 0; r < 4; ++r) {
        const int row = m0 + wr * 64 + i * 16 + lg * 4 + r;
        const float v = acc[i][j][r] + bv;
        if (OUT_F32) Cf[(size_t)row * N + col] = v;
        else         Cb[(size_t)row * N + col] = f2bf(v);
      }
    }
  }
}

// ----------------------------------------------------- causal flash attention
// R21 structure (8-wave blocks x 128 q-rows; KVBLK=128 staged as 2x64-key
// subtiles, 17 barriers/block; pre-swizzled source, 0 bank conflicts;
// no-max-tracking exp2 softmax; T5 setprio around MFMA clusters). Unchanged.
__global__ __launch_bounds__(512) void attn_fwd(
    const unsigned short* __restrict__ qkv,
    const unsigned short* __restrict__ Vt,
    unsigned short* __restrict__ out)
{
  __shared__ __align__(16) char Kl[2][2][64 * 128];  // [buf][subtile][row*128+swz]
  __shared__ __align__(16) char Vl[2][2][64 * 128];  // rows = d, cols = key

  const int bid = blockIdx.x;
  const int bh = bid & 63;               // XCD = bh % 8 stable
  const int slot = bid >> 6;             // 0..7
  const int b = bh >> 4, h = bh & 15;
  const int w = threadIdx.x >> 6, l = threadIdx.x & 63;   // w 0..7
  const int lr = l & 15, lg = l >> 4;

  const size_t rs = N3D;
  const unsigned short* Qb = qkv + (size_t)b * NS * rs + (size_t)h * NDH;
  const unsigned short* Kb = Qb + ND;
  const unsigned short* VtB = Vt + (size_t)bh * NDH * NS;

  const int srow = l >> 3;                               // 0..7
  const int sw = (((l & 7) * 16) ^ (srow << 4)) >> 1;    // element offset
  const unsigned short* KsrcBase = Kb + (size_t)(8 * w + srow) * rs + sw;
  const unsigned short* VsrcBase = VtB + (size_t)(8 * w + srow) * NS + sw;
  const int ldsRow0 = (8 * w) * 128;                     // wave's dest base

  const float QSCALE = 0.125f * 1.44269504f;   // exp2-domain
  const int ksw = (lr & 7) << 4;               // read-side XOR swizzle

  #pragma unroll 1
  for (int pass = 0; pass < 2; ++pass) {
    const int qt = pass == 0 ? slot : 15 - slot;   // q-tile 0..15 (128 rows)
    const int q0 = qt * 128 + w * 16;              // wave's 16 q-rows
    const int T2 = qt + 1;                         // 128-key tiles this pass

    // Q fragment for rows q0+lr, pre-scaled (bf16 round, ~0.2% rel err)
    short8 qf[2];
    {
      const unsigned short* qrow = Qb + (size_t)(q0 + lr) * rs + lg * 8;
      qf[0] = *(const short8*)(qrow);
      qf[1] = *(const short8*)(qrow + 32);
      #pragma unroll
      for (int j = 0; j < 8; ++j) {
        qf[0][j] = (short)f2bf(bf2f((unsigned short)qf[0][j]) * QSCALE);
        qf[1][j] = (short)f2bf(bf2f((unsigned short)qf[1][j]) * QSCALE);
      }
    }

    float l_run = 0.f;                 // per-lane PARTIAL row sum
    f32x4 o[4] = {};

    auto stage = [&](int buf, int kt2) {
      const int kb = kt2 << 7;
      GLD16(KsrcBase + (size_t)kb * rs,        &Kl[buf][0][ldsRow0]);
      GLD16(KsrcBase + (size_t)(kb + 64) * rs, &Kl[buf][1][ldsRow0]);
      GLD16(VsrcBase + kb,                     &Vl[buf][0][ldsRow0]);
      GLD16(VsrcBase + kb + 64,                &Vl[buf][1][ldsRow0]);
    };

    stage(0, 0);
    __syncthreads();   // compiler drains vmcnt before s_barrier

    #pragma unroll 1
    for (int kt2 = 0; kt2 < T2; ++kt2) {
      const int cur = kt2 & 1;
      if (kt2 + 1 < T2) stage(cur ^ 1, kt2 + 1);   // async, lands by next barrier

      #pragma unroll
      for (int st = 0; st < 2; ++st) {
        const int kbase = kt2 * 128 + st * 64;
        if (kbase > q0 + 15) continue;   // wave-uniform: skip fully-masked

        // K fragments from LDS (swizzled ds_read_b128)
        short8 kf[4][2];
        #pragma unroll
        for (int ks = 0; ks < 4; ++ks) {
          const char* rowp = &Kl[cur][st][(ks * 16 + lr) * 128];
          kf[ks][0] = *(const short8*)(rowp + ((lg * 16) ^ ksw));
          kf[ks][1] = *(const short8*)(rowp + ((64 + lg * 16) ^ ksw));
        }

        // swapped QK^T: s[ks] = S^T[key=kbase+ks*16+lg*4+r][q=q0+lr]
        f32x4 s[4] = {};
        __builtin_amdgcn_s_setprio(1);
        #pragma unroll
        for (int ks = 0; ks < 4; ++ks) {
          s[ks] = __builtin_amdgcn_mfma_f32_16x16x32_bf16(kf[ks][0], qf[0], s[ks], 0, 0, 0);
          s[ks] = __builtin_amdgcn_mfma_f32_16x16x32_bf16(kf[ks][1], qf[1], s[ks], 0, 0, 0);
        }
        __builtin_amdgcn_s_setprio(0);

        // V fragments (ds latency overlaps the softmax VALU below)
        short8 vf[4][2];
        #pragma unroll
        for (int nb = 0; nb < 4; ++nb) {
          const char* rowp = &Vl[cur][st][(nb * 16 + lr) * 128];
          vf[nb][0] = *(const short8*)(rowp + ((lg * 16) ^ ksw));
          vf[nb][1] = *(const short8*)(rowp + ((64 + lg * 16) ^ ksw));
        }

        const bool domask = (kbase + 63 > q0);   // wave-uniform (diag tiles)
        const int qi = q0 + lr;
        // un-shifted exponentials (bounded-score proof, R16); mask -> 0
        float p[16];
        if (domask) {
          #pragma unroll
          for (int ks = 0; ks < 4; ++ks)
            #pragma unroll
            for (int r = 0; r < 4; ++r)
              p[ks * 4 + r] = (kbase + ks * 16 + lg * 4 + r > qi)
                                ? 0.f : exp2f(s[ks][r]);
        } else {
          #pragma unroll
          for (int ks = 0; ks < 4; ++ks)
            #pragma unroll
            for (int r = 0; r < 4; ++r)
              p[ks * 4 + r] = exp2f(s[ks][r]);
        }
        // per-lane PARTIAL row sum (no shuffles; reduced once in epilogue)
        float s0 = (p[0] + p[1]) + (p[2] + p[3]);
        float s1 = (p[4] + p[5]) + (p[6] + p[7]);
        float s2 = (p[8] + p[9]) + (p[10] + p[11]);
        float s3 = (p[12] + p[13]) + (p[14] + p[15]);
        l_run += (s0 + s1) + (s2 + s3);

        // pack P to bf16 pairs: A_ks = keys ks*16+lg*4+{0,1}, B_ks = {2,3}
        unsigned A0 = cvtpk_bf16(p[0],  p[1]),  B0 = cvtpk_bf16(p[2],  p[3]);
        unsigned A1 = cvtpk_bf16(p[4],  p[5]),  B1 = cvtpk_bf16(p[6],  p[7]);
        unsigned A2 = cvtpk_bf16(p[8],  p[9]),  B2 = cvtpk_bf16(p[10], p[11]);
        unsigned A3 = cvtpk_bf16(p[12], p[13]), B3 = cvtpk_bf16(p[14], p[15]);

        // in-register transpose to PV A-fragment layout (VALU, no LDS)
        asm("v_permlane32_swap_b32 %0, %1" : "+v"(A0), "+v"(A1));
        asm("v_permlane16_swap_b32 %0, %1" : "+v"(A0), "+v"(A1));
        asm("v_permlane32_swap_b32 %0, %1" : "+v"(B0), "+v"(B1));
        asm("v_permlane16_swap_b32 %0, %1" : "+v"(B0), "+v"(B1));
        asm("v_permlane32_swap_b32 %0, %1" : "+v"(A2), "+v"(A3));
        asm("v_permlane16_swap_b32 %0, %1" : "+v"(A2), "+v"(A3));
        asm("v_permlane32_swap_b32 %0, %1" : "+v"(B2), "+v"(B3));
        asm("v_permlane16_swap_b32 %0, %1" : "+v"(B2), "+v"(B3));

        uint4v u0 = {A0, B0, A1, B1};   // pf0: keys lg*8+0..7
        uint4v u1 = {A2, B2, A3, B3};   // pf1: keys 32+lg*8+0..7
        short8 pf0 = __builtin_bit_cast(short8, u0);
        short8 pf1 = __builtin_bit_cast(short8, u1);

        __builtin_amdgcn_s_setprio(1);
        #pragma unroll
        for (int nb = 0; nb < 4; ++nb)
          o[nb] = __builtin_amdgcn_mfma_f32_16x16x32_bf16(pf0, vf[nb][0], o[nb], 0, 0, 0);
        #pragma unroll
        for (int nb = 0; nb < 4; ++nb)
          o[nb] = __builtin_amdgcn_mfma_f32_16x16x32_bf16(pf1, vf[nb][1], o[nb], 0, 0, 0);
        __builtin_amdgcn_s_setprio(0);
      }

      __syncthreads();   // joins waves; drains vmcnt (stage done) + LDS reads
    }

    // epilogue: reduce the per-lane l_run partials (once per pass), normalize
    {
      float lt = l_run;
      lt += __shfl_xor(lt, 16);
      lt += __shfl_xor(lt, 32);
      #pragma unroll
      for (int rr = 0; rr < 4; ++rr) {
        const float lq = __shfl(lt, lg * 4 + rr);
        const float inv = 1.0f / lq;
        const int qi = q0 + lg * 4 + rr;
        #pragma unroll
        for (int nb = 0; nb < 4; ++nb)
          out[(size_t)(b * NS + qi) * ND + h * NDH + nb * 16 + lr] = f2bf(o[nb][rr] * inv);
      }
    }
  }
}

// --------------------------------------------------------------------- launch
extern "C" void kernel_launch(void* const* d_in, const int* in_sizes, int n_in,
                              void* d_out, int out_size, void* d_ws, size_t ws_size,
                              hipStream_t stream) {
  const float* x     = (const float*)d_in[0];
  const float* w_in  = (const float*)d_in[1];
  const float* b_in  = (const float*)d_in[2];
  const float* w_out = (const float*)d_in[3];
  const float* b_out = (const float*)d_in[4];
  float* out = (float*)d_out;

  char* ws = (char*)d_ws;
  size_t off = 0;
  unsigned short* x_bf    = (unsigned short*)(ws + off); off += (size_t)NM * ND * 2;    // 16 MiB
  unsigned short* qkv     = (unsigned short*)(ws + off); off += (size_t)NM * N3D * 2;   // 48 MiB
  unsigned short* attn    = (unsigned short*)(ws + off); off += (size_t)NM * ND * 2;    // 16 MiB
  unsigned short* w_in_t  = (unsigned short*)(ws + off); off += (size_t)N3D * ND * 2;   //  6 MiB
  unsigned short* w_out_t = (unsigned short*)(ws + off); off += (size_t)ND * ND * 2;    //  2 MiB
  // Vt aliases x_bf: x_bf is dead after GEMM1, vt_transpose runs after GEMM1.
  unsigned short* vt = x_bf;                                                            // 16 MiB

  // x -> bf16
  cvt_bf16_k<<<dim3((NM * ND) / (256 * 4)), 256, 0, stream>>>(x, x_bf, NM * ND);
  // weight transposes + cast: w[K][N] f32 -> wt[N][K] bf16
  transpose_cvt_k<<<dim3(N3D / 32, ND / 32), 256, 0, stream>>>(w_in, w_in_t, ND, N3D);
  transpose_cvt_k<<<dim3(ND / 32, ND / 32), 256, 0, stream>>>(w_out, w_out_t, ND, ND);

  // qkv = x @ w_in + b_in            (bf16 out)
  gemm_bt_bias<false><<<dim3((NM / 128) * (N3D / 128)), 256, 0, stream>>>(
      x_bf, w_in_t, b_in, qkv, nullptr, NM, N3D, ND);

  // V -> Vt (transposed per head)
  vt_transpose_k<<<dim3(64 * 64 * 2), 256, 0, stream>>>(qkv, vt);

  // attention: 512 blocks x 512 threads (8 waves, 128 q-rows; pairing qt/15-qt)
  attn_fwd<<<dim3(64 * 8), 512, 0, stream>>>(qkv, vt, attn);

  // out = attn @ w_out + b_out       (f32 out)
  gemm_bt_bias<true><<<dim3((NM / 128) * (ND / 128)), 256, 0, stream>>>(
      attn, w_out_t, b_out, nullptr, out, NM, ND, ND);
}